// Round 2
// baseline (671.180 us; speedup 1.0000x reference)
//
#include <hip/hip_runtime.h>
#include <stdint.h>
#include <stddef.h>

#define NTOK 8192
#define DDIM 1024
#define NEXP 8
#define HDIM 2048
#define MAXROWS (2 * NTOK + NEXP * 128) /* 17408 compacted+padded expert rows */

typedef __attribute__((ext_vector_type(4))) float f32x4;
typedef __attribute__((ext_vector_type(8))) short s16x8;
typedef __attribute__((ext_vector_type(4))) short s16x4;

static __device__ __forceinline__ unsigned short f2bf(float f) {
  union { float f; unsigned u; } v; v.f = f;
  unsigned r = v.u + 0x7FFFu + ((v.u >> 16) & 1u); // RNE
  return (unsigned short)(r >> 16);
}
static __device__ __forceinline__ float bf2f(unsigned short h) {
  union { unsigned u; float f; } v; v.u = ((unsigned)h) << 16;
  return v.f;
}

static __device__ __forceinline__ void gll16(const void* g, void* l) {
  __builtin_amdgcn_global_load_lds((const __attribute__((address_space(1))) void*)g,
                                   (__attribute__((address_space(3))) void*)l, 16, 0, 0);
}

__global__ void k_sentinel(float* out) { if (threadIdx.x == 0) out[0] = 1.0e6f; }

// ---- fp32 -> bf16 bulk convert; n8 = count/8 ----
__global__ __launch_bounds__(256) void k_cvt(const float* __restrict__ src,
                                             unsigned short* __restrict__ dst, int n8) {
  int i = blockIdx.x * blockDim.x + threadIdx.x;
  int stride = gridDim.x * blockDim.x;
  for (; i < n8; i += stride) {
    const f32x4* s = (const f32x4*)(src + (size_t)i * 8);
    f32x4 a = s[0], b = s[1];
    s16x8 o;
    o[0] = f2bf(a[0]); o[1] = f2bf(a[1]); o[2] = f2bf(a[2]); o[3] = f2bf(a[3]);
    o[4] = f2bf(b[0]); o[5] = f2bf(b[1]); o[6] = f2bf(b[2]); o[7] = f2bf(b[3]);
    *(s16x8*)(dst + (size_t)i * 8) = o;
  }
}

// ---- router: fp32 logits, top-2 (lower-index tie-break), softmax, list append.
//      Also emits xbf (fused fp32->bf16 conversion of x). ----
__global__ __launch_bounds__(256) void k_router(const float* __restrict__ x,
    const float* __restrict__ gw, int* __restrict__ cnt,
    int* __restrict__ listTok, float* __restrict__ listW, int* __restrict__ listSlot,
    unsigned short* __restrict__ xbf) {
  int lane = threadIdx.x & 63;
  int t = blockIdx.x * 4 + (threadIdx.x >> 6);
  const f32x4* x4 = (const f32x4*)x;
  const f32x4* g4 = (const f32x4*)gw;
  f32x4 xr[4];
#pragma unroll
  for (int j = 0; j < 4; ++j) xr[j] = x4[(size_t)t * 256 + j * 64 + lane];
  // fused conversion of x to bf16
#pragma unroll
  for (int j = 0; j < 4; ++j) {
    s16x4 o;
    o[0] = f2bf(xr[j][0]); o[1] = f2bf(xr[j][1]); o[2] = f2bf(xr[j][2]); o[3] = f2bf(xr[j][3]);
    *(s16x4*)(xbf + (size_t)t * DDIM + (j * 64 + lane) * 4) = o;
  }
  float le[8];
#pragma unroll
  for (int e = 0; e < 8; ++e) {
    float p = 0.f;
#pragma unroll
    for (int j = 0; j < 4; ++j) {
      f32x4 g = g4[e * 256 + j * 64 + lane];
      p += xr[j][0] * g[0] + xr[j][1] * g[1] + xr[j][2] * g[2] + xr[j][3] * g[3];
    }
#pragma unroll
    for (int off = 32; off > 0; off >>= 1) p += __shfl_xor(p, off, 64);
    le[e] = p;
  }
  if (lane == 0) {
    int i0 = 0; float v0 = le[0];
#pragma unroll
    for (int e = 1; e < 8; ++e) if (le[e] > v0) { v0 = le[e]; i0 = e; }
    int i1 = -1; float v1 = 0.f;
#pragma unroll
    for (int e = 0; e < 8; ++e) if (e != i0 && (i1 < 0 || le[e] > v1)) { v1 = le[e]; i1 = e; }
    float b = __expf(v1 - v0);
    float s = 1.f + b;
    int p0 = atomicAdd(&cnt[i0], 1);
    listTok[i0 * NTOK + p0] = t; listW[i0 * NTOK + p0] = 1.f / s; listSlot[i0 * NTOK + p0] = 0;
    int p1 = atomicAdd(&cnt[i1], 1);
    listTok[i1 * NTOK + p1] = t; listW[i1 * NTOK + p1] = b / s; listSlot[i1 * NTOK + p1] = 1;
  }
}

// ---- rowbase prefix (counts rounded up to 128) ----
__global__ void k_prefix(int* ctrl) {
  if (threadIdx.x == 0) {
    int acc = 0;
#pragma unroll
    for (int e = 0; e < NEXP; ++e) { ctrl[8 + e] = acc; acc += (ctrl[e] + 127) & ~127; }
  }
}

// ---- GEMM1: h = silu(Xg @ Wg^T) * (Xg @ Wi^T), gathered rows, bf16 out ----
// tile 128(M) x 64(Ncols of H) x BK=64; 4 waves in 2x2; dual accumulators
__global__ __launch_bounds__(256) void k_gemm1(const unsigned short* __restrict__ xbf,
    const unsigned short* __restrict__ wg, const unsigned short* __restrict__ wi,
    const int* __restrict__ ctrl, const int* __restrict__ listTok,
    unsigned short* __restrict__ hbuf) {
  int e = blockIdx.z;
  int cnt = ctrl[e];
  int m0 = blockIdx.y * 128;
  if (m0 >= cnt) return;
  int rowb = ctrl[8 + e];
  int n0 = blockIdx.x * 64;

  __shared__ unsigned short lA[128 * 64];   // 16 KB
  __shared__ unsigned short lBg[64 * 64];   //  8 KB
  __shared__ unsigned short lBi[64 * 64];   //  8 KB

  int tid = threadIdx.x, lane = tid & 63;
  int wv = tid >> 6, wr = wv >> 1, wc = wv & 1;
  int rrow = tid >> 3;            // 0..31 staging row within round
  int rcol = (tid & 7) * 8;       // elem col within 64-wide K slab

  // gather sources: token rows (pad rows read token 0 - listTok zero-initialized)
  const unsigned short* srcA[4];
#pragma unroll
  for (int r = 0; r < 4; ++r) {
    int tok = listTok[e * NTOK + m0 + r * 32 + rrow];
    srcA[r] = xbf + (size_t)tok * DDIM + rcol;
  }
  const unsigned short* srcBg[2];
  const unsigned short* srcBi[2];
#pragma unroll
  for (int r = 0; r < 2; ++r) {
    srcBg[r] = wg + ((size_t)e * HDIM + n0 + r * 32 + rrow) * DDIM + rcol;
    srcBi[r] = wi + ((size_t)e * HDIM + n0 + r * 32 + rrow) * DDIM + rcol;
  }
  unsigned ldsAoff  = ((unsigned)rrow * 64 + rcol) * 2;   // byte offsets, +r*32 rows
  unsigned ldsBoff  = ldsAoff;

  // fragment read offsets (elements)
  int aoff[4], boff[2];
#pragma unroll
  for (int f = 0; f < 4; ++f) aoff[f] = (wr * 64 + f * 16 + (lane & 15)) * 64 + (lane >> 4) * 8;
#pragma unroll
  for (int f = 0; f < 2; ++f) boff[f] = (wc * 32 + f * 16 + (lane & 15)) * 64 + (lane >> 4) * 8;

  f32x4 accg[4][2], acci[4][2];
#pragma unroll
  for (int i = 0; i < 4; ++i)
#pragma unroll
    for (int j = 0; j < 2; ++j) {
      accg[i][j] = (f32x4){0.f, 0.f, 0.f, 0.f};
      acci[i][j] = (f32x4){0.f, 0.f, 0.f, 0.f};
    }

  for (int k0 = 0; k0 < DDIM; k0 += 64) {
#pragma unroll
    for (int r = 0; r < 4; ++r) gll16(srcA[r] + k0, (char*)lA + (r * 32 * 64 * 2) + ldsAoff);
#pragma unroll
    for (int r = 0; r < 2; ++r) {
      gll16(srcBg[r] + k0, (char*)lBg + (r * 32 * 64 * 2) + ldsBoff);
      gll16(srcBi[r] + k0, (char*)lBi + (r * 32 * 64 * 2) + ldsBoff);
    }
    __syncthreads();   // compiler drains vmcnt before barrier -> LDS tile ready
#pragma unroll
    for (int ks = 0; ks < 2; ++ks) {
      s16x8 a[4], bg[2], bi[2];
#pragma unroll
      for (int f = 0; f < 4; ++f) a[f] = *(const s16x8*)&lA[aoff[f] + ks * 32];
#pragma unroll
      for (int f = 0; f < 2; ++f) {
        bg[f] = *(const s16x8*)&lBg[boff[f] + ks * 32];
        bi[f] = *(const s16x8*)&lBi[boff[f] + ks * 32];
      }
#pragma unroll
      for (int fm = 0; fm < 4; ++fm)
#pragma unroll
        for (int fn = 0; fn < 2; ++fn) {
          accg[fm][fn] = __builtin_amdgcn_mfma_f32_16x16x32_bf16(a[fm], bg[fn], accg[fm][fn], 0, 0, 0);
          acci[fm][fn] = __builtin_amdgcn_mfma_f32_16x16x32_bf16(a[fm], bi[fn], acci[fm][fn], 0, 0, 0);
        }
    }
    __syncthreads();   // all waves done reading before next stage overwrites
  }

#pragma unroll
  for (int fm = 0; fm < 4; ++fm)
#pragma unroll
    for (int fn = 0; fn < 2; ++fn)
#pragma unroll
      for (int j = 0; j < 4; ++j) {
        int r = wr * 64 + fm * 16 + ((lane >> 4) << 2) + j;   // C/D: row=(lane>>4)*4+j
        int cc = wc * 32 + fn * 16 + (lane & 15);             //      col=lane&15
        float g = accg[fm][fn][j];
        float iv = acci[fm][fn][j];
        float hv = g / (1.f + __expf(-g)) * iv;               // silu(g)*i in fp32
        hbuf[(size_t)(rowb + m0 + r) * HDIM + n0 + cc] = f2bf(hv);
      }
}

// ---- GEMM2: y[slot][token] = w * (h @ Wo^T); tile 128x128xBK=64, no atomics ----
__global__ __launch_bounds__(256) void k_gemm2(const unsigned short* __restrict__ hbuf,
    const unsigned short* __restrict__ wo, const int* __restrict__ ctrl,
    const int* __restrict__ listTok, const float* __restrict__ listW,
    const int* __restrict__ listSlot, unsigned short* __restrict__ ybuf) {
  int e = blockIdx.z;
  int cnt = ctrl[e];
  int m0 = blockIdx.y * 128;
  if (m0 >= cnt) return;
  int rowb = ctrl[8 + e];
  int n0 = blockIdx.x * 128;

  __shared__ unsigned short lA[128 * 64];   // 16 KB
  __shared__ unsigned short lB[128 * 64];   // 16 KB

  int tid = threadIdx.x, lane = tid & 63;
  int wv = tid >> 6, wr = wv >> 1, wc = wv & 1;
  int rrow = tid >> 3;
  int rcol = (tid & 7) * 8;

  const unsigned short* srcA = hbuf + ((size_t)(rowb + m0 + rrow)) * HDIM + rcol;
  const unsigned short* srcB = wo + ((size_t)e * DDIM + n0 + rrow) * HDIM + rcol;
  unsigned ldsOff = ((unsigned)rrow * 64 + rcol) * 2;

  int aoff[4], boff[4];
#pragma unroll
  for (int f = 0; f < 4; ++f) {
    aoff[f] = (wr * 64 + f * 16 + (lane & 15)) * 64 + (lane >> 4) * 8;
    boff[f] = (wc * 64 + f * 16 + (lane & 15)) * 64 + (lane >> 4) * 8;
  }

  f32x4 acc[4][4];
#pragma unroll
  for (int i = 0; i < 4; ++i)
#pragma unroll
    for (int j = 0; j < 4; ++j) acc[i][j] = (f32x4){0.f, 0.f, 0.f, 0.f};

  for (int k0 = 0; k0 < HDIM; k0 += 64) {
#pragma unroll
    for (int r = 0; r < 4; ++r) {
      gll16(srcA + (size_t)r * 32 * HDIM + k0, (char*)lA + (r * 32 * 64 * 2) + ldsOff);
      gll16(srcB + (size_t)r * 32 * HDIM + k0, (char*)lB + (r * 32 * 64 * 2) + ldsOff);
    }
    __syncthreads();
#pragma unroll
    for (int ks = 0; ks < 2; ++ks) {
      s16x8 a[4], b[4];
#pragma unroll
      for (int f = 0; f < 4; ++f) {
        a[f] = *(const s16x8*)&lA[aoff[f] + ks * 32];
        b[f] = *(const s16x8*)&lB[boff[f] + ks * 32];
      }
#pragma unroll
      for (int fm = 0; fm < 4; ++fm)
#pragma unroll
        for (int fn = 0; fn < 4; ++fn)
          acc[fm][fn] = __builtin_amdgcn_mfma_f32_16x16x32_bf16(a[fm], b[fn], acc[fm][fn], 0, 0, 0);
    }
    __syncthreads();
  }

#pragma unroll
  for (int fm = 0; fm < 4; ++fm)
#pragma unroll
    for (int j = 0; j < 4; ++j) {
      int r = wr * 64 + fm * 16 + ((lane >> 4) << 2) + j;
      int mrow = m0 + r;
      if (mrow < cnt) {
        int tok = listTok[e * NTOK + mrow];
        float wgt = listW[e * NTOK + mrow];
        int slot = listSlot[e * NTOK + mrow];
        size_t base = ((size_t)slot * NTOK + tok) * DDIM + n0 + wc * 64;
#pragma unroll
        for (int fn = 0; fn < 4; ++fn)
          ybuf[base + fn * 16 + (lane & 15)] = f2bf(acc[fm][fn][j] * wgt);
      }
    }
}

// ---- reduce: out = y0 + y1 (fp32 out), vectorized ----
__global__ __launch_bounds__(256) void k_reduce(const unsigned short* __restrict__ ybuf,
                                                float* __restrict__ out, int n8) {
  int i = blockIdx.x * blockDim.x + threadIdx.x;
  int stride = gridDim.x * blockDim.x;
  const unsigned short* y0 = ybuf;
  const unsigned short* y1 = ybuf + (size_t)NTOK * DDIM;
  for (; i < n8; i += stride) {
    s16x8 a = *(const s16x8*)(y0 + (size_t)i * 8);
    s16x8 b = *(const s16x8*)(y1 + (size_t)i * 8);
    f32x4 o0, o1;
#pragma unroll
    for (int j = 0; j < 4; ++j) o0[j] = bf2f((unsigned short)a[j]) + bf2f((unsigned short)b[j]);
#pragma unroll
    for (int j = 0; j < 4; ++j) o1[j] = bf2f((unsigned short)a[4 + j]) + bf2f((unsigned short)b[4 + j]);
    f32x4* d = (f32x4*)(out + (size_t)i * 8);
    d[0] = o0; d[1] = o1;
  }
}

extern "C" void kernel_launch(void* const* d_in, const int* in_sizes, int n_in,
                              void* d_out, int out_size, void* d_ws, size_t ws_size,
                              hipStream_t stream) {
  const float* x     = (const float*)d_in[0];
  const float* gw    = (const float*)d_in[1];
  const float* wgate = (const float*)d_in[2];
  const float* win   = (const float*)d_in[3];
  const float* wout  = (const float*)d_in[4];
  float* out = (float*)d_out;

  const size_t OFF_LIST   = 256;
  const size_t OFF_LISTW  = OFF_LIST + (size_t)NEXP * NTOK * 4;
  const size_t OFF_SLOT   = OFF_LISTW + (size_t)NEXP * NTOK * 4;
  const size_t ZERO_BYTES = OFF_LISTW;                       // ctrl + listTok must be zeroed
  const size_t OFF_XBF = (size_t)1 << 20;
  const size_t OFF_WG  = OFF_XBF + (size_t)NTOK * DDIM * 2;
  const size_t OFF_WI  = OFF_WG + (size_t)NEXP * HDIM * DDIM * 2;
  const size_t OFF_WO  = OFF_WI + (size_t)NEXP * HDIM * DDIM * 2;
  const size_t OFF_H   = OFF_WO + (size_t)NEXP * DDIM * HDIM * 2;
  const size_t OFF_Y   = OFF_H + (size_t)MAXROWS * HDIM * 2;
  const size_t TOTAL   = OFF_Y + (size_t)2 * NTOK * DDIM * 2;

  if (ws_size < TOTAL) { k_sentinel<<<1, 64, 0, stream>>>(out); return; }

  char* ws = (char*)d_ws;
  int* ctrl            = (int*)ws;                       // [0..7]=cnt, [8..15]=rowbase
  int* listTok         = (int*)(ws + OFF_LIST);
  float* listW         = (float*)(ws + OFF_LISTW);
  int* listSlot        = (int*)(ws + OFF_SLOT);
  unsigned short* xbf  = (unsigned short*)(ws + OFF_XBF);
  unsigned short* wgb  = (unsigned short*)(ws + OFF_WG);
  unsigned short* wib  = (unsigned short*)(ws + OFF_WI);
  unsigned short* wob  = (unsigned short*)(ws + OFF_WO);
  unsigned short* hbuf = (unsigned short*)(ws + OFF_H);
  unsigned short* ybuf = (unsigned short*)(ws + OFF_Y);

  hipMemsetAsync(ws, 0, ZERO_BYTES, stream);   // counts + token lists (pad-row safety)

  k_cvt<<<2048, 256, 0, stream>>>(wgate, wgb, NEXP * HDIM * DDIM / 8);
  k_cvt<<<2048, 256, 0, stream>>>(win,   wib, NEXP * HDIM * DDIM / 8);
  k_cvt<<<2048, 256, 0, stream>>>(wout,  wob, NEXP * DDIM * HDIM / 8);

  k_router<<<NTOK / 4, 256, 0, stream>>>(x, gw, ctrl, listTok, listW, listSlot, xbf);
  k_prefix<<<1, 64, 0, stream>>>(ctrl);

  k_gemm1<<<dim3(HDIM / 64, NTOK / 128, NEXP), 256, 0, stream>>>(xbf, wgb, wib, ctrl, listTok, hbuf);
  k_gemm2<<<dim3(DDIM / 128, NTOK / 128, NEXP), 256, 0, stream>>>(hbuf, wob, ctrl, listTok, listW, listSlot, ybuf);
  k_reduce<<<2048, 256, 0, stream>>>(ybuf, out, NTOK * DDIM / 8);
}

// Round 3
// 542.319 us; speedup vs baseline: 1.2376x; 1.2376x over previous
//
#include <hip/hip_runtime.h>
#include <stdint.h>
#include <stddef.h>

#define NTOK 8192
#define DDIM 1024
#define NEXP 8
#define HDIM 2048
#define LSTRIDE (NTOK + 256)
#define MAXROWS (2 * NTOK + NEXP * 256) /* 18432 compacted rows, 256-padded */

typedef __attribute__((ext_vector_type(4))) float f32x4;
typedef __attribute__((ext_vector_type(8))) short s16x8;
typedef __attribute__((ext_vector_type(4))) short s16x4;

static __device__ __forceinline__ unsigned short f2bf(float f) {
  union { float f; unsigned u; } v; v.f = f;
  unsigned r = v.u + 0x7FFFu + ((v.u >> 16) & 1u); // RNE
  return (unsigned short)(r >> 16);
}
static __device__ __forceinline__ float bf2f(unsigned short h) {
  union { unsigned u; float f; } v; v.u = ((unsigned)h) << 16;
  return v.f;
}

static __device__ __forceinline__ void gll16(const void* g, void* l) {
  __builtin_amdgcn_global_load_lds((const __attribute__((address_space(1))) void*)g,
                                   (__attribute__((address_space(3))) void*)l, 16, 0, 0);
}

#define BAR_MID() __builtin_amdgcn_s_barrier()
#define BAR_END() do { __builtin_amdgcn_s_barrier(); __builtin_amdgcn_sched_barrier(0); } while (0)
#define LGKM0() do { asm volatile("s_waitcnt lgkmcnt(0)" ::: "memory"); __builtin_amdgcn_sched_barrier(0); } while (0)
#define VMW6() asm volatile("s_waitcnt vmcnt(6)" ::: "memory")
#define VMW0() asm volatile("s_waitcnt vmcnt(0)" ::: "memory")

__global__ void k_sentinel(float* out) { if (threadIdx.x == 0) out[0] = 1.0e6f; }

// ---- fp32 -> bf16 bulk convert; n8 = count/8 ----
__global__ __launch_bounds__(256) void k_cvt(const float* __restrict__ src,
                                             unsigned short* __restrict__ dst, int n8) {
  int i = blockIdx.x * blockDim.x + threadIdx.x;
  int stride = gridDim.x * blockDim.x;
  for (; i < n8; i += stride) {
    const f32x4* s = (const f32x4*)(src + (size_t)i * 8);
    f32x4 a = s[0], b = s[1];
    s16x8 o;
    o[0] = f2bf(a[0]); o[1] = f2bf(a[1]); o[2] = f2bf(a[2]); o[3] = f2bf(a[3]);
    o[4] = f2bf(b[0]); o[5] = f2bf(b[1]); o[6] = f2bf(b[2]); o[7] = f2bf(b[3]);
    *(s16x8*)(dst + (size_t)i * 8) = o;
  }
}

// ---- router: fp32 logits, top-2 (lower-index tie-break), softmax, list append.
//      Also emits xbf (fused fp32->bf16 conversion of x). ----
__global__ __launch_bounds__(256) void k_router(const float* __restrict__ x,
    const float* __restrict__ gw, int* __restrict__ cnt,
    int* __restrict__ listTok, float* __restrict__ listW, int* __restrict__ listSlot,
    unsigned short* __restrict__ xbf) {
  int lane = threadIdx.x & 63;
  int t = blockIdx.x * 4 + (threadIdx.x >> 6);
  const f32x4* x4 = (const f32x4*)x;
  const f32x4* g4 = (const f32x4*)gw;
  f32x4 xr[4];
#pragma unroll
  for (int j = 0; j < 4; ++j) xr[j] = x4[(size_t)t * 256 + j * 64 + lane];
#pragma unroll
  for (int j = 0; j < 4; ++j) {
    s16x4 o;
    o[0] = f2bf(xr[j][0]); o[1] = f2bf(xr[j][1]); o[2] = f2bf(xr[j][2]); o[3] = f2bf(xr[j][3]);
    *(s16x4*)(xbf + (size_t)t * DDIM + (j * 64 + lane) * 4) = o;
  }
  float le[8];
#pragma unroll
  for (int e = 0; e < 8; ++e) {
    float p = 0.f;
#pragma unroll
    for (int j = 0; j < 4; ++j) {
      f32x4 g = g4[e * 256 + j * 64 + lane];
      p += xr[j][0] * g[0] + xr[j][1] * g[1] + xr[j][2] * g[2] + xr[j][3] * g[3];
    }
#pragma unroll
    for (int off = 32; off > 0; off >>= 1) p += __shfl_xor(p, off, 64);
    le[e] = p;
  }
  if (lane == 0) {
    int i0 = 0; float v0 = le[0];
#pragma unroll
    for (int e = 1; e < 8; ++e) if (le[e] > v0) { v0 = le[e]; i0 = e; }
    int i1 = -1; float v1 = 0.f;
#pragma unroll
    for (int e = 0; e < 8; ++e) if (e != i0 && (i1 < 0 || le[e] > v1)) { v1 = le[e]; i1 = e; }
    float b = __expf(v1 - v0);
    float s = 1.f + b;
    int p0 = atomicAdd(&cnt[i0], 1);
    listTok[i0 * LSTRIDE + p0] = t; listW[i0 * LSTRIDE + p0] = 1.f / s; listSlot[i0 * LSTRIDE + p0] = 0;
    int p1 = atomicAdd(&cnt[i1], 1);
    listTok[i1 * LSTRIDE + p1] = t; listW[i1 * LSTRIDE + p1] = b / s; listSlot[i1 * LSTRIDE + p1] = 1;
  }
}

// ---- rowbase prefix (counts rounded up to 256) ----
__global__ void k_prefix(int* ctrl) {
  if (threadIdx.x == 0) {
    int acc = 0;
#pragma unroll
    for (int e = 0; e < NEXP; ++e) { ctrl[8 + e] = acc; acc += (ctrl[e] + 255) & ~255; }
  }
}

// =====================================================================
// GEMM1: h = silu(Xg @ Wg^T) * (Xg @ Wi^T)
// 8-phase schedule, BM=256, BN(h)=128 dual, BK=64, 8 waves (4M x 2N),
// per-wave 64x64 of g AND i. LDS: bufA/bufB K-tiles, each {Bg,Bi,A0,A1}
// half-tiles of 16 KB, 128 KiB total. XOR swizzle (row&7)<<4 via
// inverse-swizzled global source + swizzled ds_read.
// =====================================================================
__global__ __launch_bounds__(512, 2) void k_gemm1(const unsigned short* __restrict__ xbf,
    const unsigned short* __restrict__ wg, const unsigned short* __restrict__ wi,
    const int* __restrict__ ctrl, const int* __restrict__ listTok,
    unsigned short* __restrict__ hbuf) {
  int e = blockIdx.z;
  int cnt = ctrl[e];
  int m0 = blockIdx.y * 256;
  if (m0 >= cnt) return;
  int rowb = ctrl[8 + e];
  int n0 = blockIdx.x * 128;

  __shared__ __align__(16) char lds[131072];
  char* ldsc = &lds[0];

  int tid = threadIdx.x, lane = tid & 63, wv = tid >> 6;
  int wm = wv >> 1, wn = wv & 1;

  // stage setup: thread stages 16B; row within half-tile = sub*64 + (tid>>3)
  int srow = tid >> 3;
  int scol = (((tid & 7) ^ ((tid >> 3) & 7)) << 4);  // inverse-swizzled source col byte
  int sdst = wv << 10;                               // wave-uniform LDS dest
  const char* pA[2][2];
  const char* pBg[2];
  const char* pBi[2];
#pragma unroll
  for (int rg = 0; rg < 2; ++rg)
#pragma unroll
    for (int sb = 0; sb < 2; ++sb) {
      int tok = listTok[e * LSTRIDE + m0 + rg * 128 + sb * 64 + srow];
      pA[rg][sb] = (const char*)xbf + (size_t)tok * 2048 + scol;
    }
#pragma unroll
  for (int sb = 0; sb < 2; ++sb) {
    pBg[sb] = (const char*)wg + ((size_t)e * HDIM + n0 + sb * 64 + srow) * 2048 + scol;
    pBi[sb] = (const char*)wi + ((size_t)e * HDIM + n0 + sb * 64 + srow) * 2048 + scol;
  }

  // read-side swizzled invariants
  int rowB = (lane & 15) << 7;
  int mk = (lane & 7) << 4;
  int q16 = (lane >> 4) << 4;
  int c0 = q16 ^ mk, c1 = (q16 + 64) ^ mk;
  int aO0 = 32768 + (wm >> 1) * 16384 + ((wm & 1) * 64) * 128 + rowB + c0;
  int aO1 = aO0 - c0 + c1;
  int gO0 = (wn * 64) * 128 + rowB + c0;
  int gO1 = gO0 - c0 + c1;
  int iO0 = 16384 + (wn * 64) * 128 + rowB + c0;
  int iO1 = iO0 - c0 + c1;

#define G1_STA(BUF, RG, KO) do { \
    gll16(pA[RG][0] + (KO), ldsc + (BUF) + 32768 + (RG) * 16384 + sdst); \
    gll16(pA[RG][1] + (KO), ldsc + (BUF) + 32768 + (RG) * 16384 + 8192 + sdst); } while (0)
#define G1_STG(BUF, KO) do { \
    gll16(pBg[0] + (KO), ldsc + (BUF) + sdst); \
    gll16(pBg[1] + (KO), ldsc + (BUF) + 8192 + sdst); } while (0)
#define G1_STI(BUF, KO) do { \
    gll16(pBi[0] + (KO), ldsc + (BUF) + 16384 + sdst); \
    gll16(pBi[1] + (KO), ldsc + (BUF) + 16384 + 8192 + sdst); } while (0)
#define G1_RDA(BUF) { _Pragma("unroll") for (int mf = 0; mf < 4; ++mf) { \
    af[mf][0] = *(const s16x8*)(ldsc + (BUF) + aO0 + mf * 2048); \
    af[mf][1] = *(const s16x8*)(ldsc + (BUF) + aO1 + mf * 2048); } }
#define G1_RDG(BUF) { _Pragma("unroll") for (int nf = 0; nf < 4; ++nf) { \
    bg[nf][0] = *(const s16x8*)(ldsc + (BUF) + gO0 + nf * 2048); \
    bg[nf][1] = *(const s16x8*)(ldsc + (BUF) + gO1 + nf * 2048); } }
#define G1_RDI(BUF) { _Pragma("unroll") for (int nf = 0; nf < 4; ++nf) { \
    bi[nf][0] = *(const s16x8*)(ldsc + (BUF) + iO0 + nf * 2048); \
    bi[nf][1] = *(const s16x8*)(ldsc + (BUF) + iO1 + nf * 2048); } }
#define G1_MMG(NH) do { __builtin_amdgcn_s_setprio(1); \
    _Pragma("unroll") for (int mf = 0; mf < 4; ++mf) _Pragma("unroll") for (int nf = 0; nf < 2; ++nf) { \
      accg[mf][(NH)*2+nf] = __builtin_amdgcn_mfma_f32_16x16x32_bf16(af[mf][0], bg[(NH)*2+nf][0], accg[mf][(NH)*2+nf], 0, 0, 0); \
      accg[mf][(NH)*2+nf] = __builtin_amdgcn_mfma_f32_16x16x32_bf16(af[mf][1], bg[(NH)*2+nf][1], accg[mf][(NH)*2+nf], 0, 0, 0); } \
    __builtin_amdgcn_s_setprio(0); } while (0)
#define G1_MMI(NH) do { __builtin_amdgcn_s_setprio(1); \
    _Pragma("unroll") for (int mf = 0; mf < 4; ++mf) _Pragma("unroll") for (int nf = 0; nf < 2; ++nf) { \
      acci[mf][(NH)*2+nf] = __builtin_amdgcn_mfma_f32_16x16x32_bf16(af[mf][0], bi[(NH)*2+nf][0], acci[mf][(NH)*2+nf], 0, 0, 0); \
      acci[mf][(NH)*2+nf] = __builtin_amdgcn_mfma_f32_16x16x32_bf16(af[mf][1], bi[(NH)*2+nf][1], acci[mf][(NH)*2+nf], 0, 0, 0); } \
    __builtin_amdgcn_s_setprio(0); } while (0)

  f32x4 accg[4][4], acci[4][4];
#pragma unroll
  for (int a = 0; a < 4; ++a)
#pragma unroll
    for (int b = 0; b < 4; ++b) { accg[a][b] = (f32x4){0.f,0.f,0.f,0.f}; acci[a][b] = (f32x4){0.f,0.f,0.f,0.f}; }
  s16x8 af[4][2], bg[4][2], bi[4][2];

  // prologue: stage iter0 items in order [aBg, aA0, aBi, aA1, bBg, bA0, bBi]
  G1_STG(0, 0); G1_STA(0, 0, 0); G1_STI(0, 0); G1_STA(0, 1, 0);
  G1_STG(65536, 128); G1_STA(65536, 0, 128); G1_STI(65536, 128);
  VMW6();
  BAR_END();

  const int NIT = DDIM / 128;  // 8 iterations x 2 K-tiles
  for (int i = 0; i < NIT; ++i) {
    const int koC = (2 * i + 1) * 128, koA = (2 * i + 2) * 128, koB = (2 * i + 3) * 128;
    const bool more = (i + 1 < NIT);
    // PH1: read a.A + a.Bg; stage b.A1 (current)
    G1_RDA(0); G1_RDG(0);
    G1_STA(65536, 1, koC);
    BAR_MID(); LGKM0();
    G1_MMG(0);
    BAR_END();
    // PH2: stage a'.Bg
    if (more) G1_STG(0, koA);
    BAR_MID();
    G1_MMG(1);
    BAR_END();
    // PH3: read a.Bi; stage a'.A0
    G1_RDI(0);
    if (more) G1_STA(0, 0, koA);
    BAR_MID(); LGKM0();
    G1_MMI(0);
    BAR_END();
    // PH4: stage a'.Bi; counted vmcnt guards b-tile reads
    if (more) G1_STI(0, koA);
    BAR_MID();
    G1_MMI(1);
    if (more) VMW6(); else VMW0();
    BAR_END();
    // PH5: read b.A + b.Bg; stage a'.A1
    G1_RDA(65536); G1_RDG(65536);
    if (more) G1_STA(0, 1, koA);
    BAR_MID(); LGKM0();
    G1_MMG(0);
    BAR_END();
    // PH6: stage b'.Bg
    if (more) G1_STG(65536, koB);
    BAR_MID();
    G1_MMG(1);
    BAR_END();
    // PH7: read b.Bi; stage b'.A0
    G1_RDI(65536);
    if (more) G1_STA(65536, 0, koB);
    BAR_MID(); LGKM0();
    G1_MMI(0);
    BAR_END();
    // PH8: stage b'.Bi; counted vmcnt guards next a-tile reads
    if (more) G1_STI(65536, koB);
    BAR_MID();
    G1_MMI(1);
    if (more) VMW6();
    BAR_END();
  }

  // epilogue: silu(g) * i -> bf16 hbuf
#pragma unroll
  for (int mf = 0; mf < 4; ++mf)
#pragma unroll
    for (int j = 0; j < 4; ++j) {
      int r = wm * 64 + mf * 16 + ((lane >> 4) << 2) + j;
      size_t rowoff = (size_t)(rowb + m0 + r) * HDIM;
#pragma unroll
      for (int nf = 0; nf < 4; ++nf) {
        int cc = n0 + wn * 64 + nf * 16 + (lane & 15);
        float g = accg[mf][nf][j];
        float iv = acci[mf][nf][j];
        float hv = g / (1.f + __expf(-g)) * iv;
        hbuf[rowoff + cc] = f2bf(hv);
      }
    }
#undef G1_STA
#undef G1_STG
#undef G1_STI
#undef G1_RDA
#undef G1_RDG
#undef G1_RDI
#undef G1_MMG
#undef G1_MMI
}

// =====================================================================
// GEMM2: y[slot][token] = w * (h @ Wo^T)
// 8-phase, BM=256, BN=256, BK=64, 8 waves (2M x 4N), per-wave 128x64.
// =====================================================================
__global__ __launch_bounds__(512, 2) void k_gemm2(const unsigned short* __restrict__ hbuf,
    const unsigned short* __restrict__ wo, const int* __restrict__ ctrl,
    const int* __restrict__ listTok, const float* __restrict__ listW,
    const int* __restrict__ listSlot, unsigned short* __restrict__ ybuf) {
  int e = blockIdx.z;
  int cnt = ctrl[e];
  int m0 = blockIdx.y * 256;
  if (m0 >= cnt) return;
  int rowb = ctrl[8 + e];
  int n0 = blockIdx.x * 256;

  __shared__ __align__(16) char lds[131072];
  char* ldsc = &lds[0];

  int tid = threadIdx.x, lane = tid & 63, wv = tid >> 6;
  int wm = wv >> 2, wn = wv & 3;

  int srow = tid >> 3;
  int scol = (((tid & 7) ^ ((tid >> 3) & 7)) << 4);
  int sdst = wv << 10;
  const char* pA[2][2];
  const char* pB[2][2];
#pragma unroll
  for (int rg = 0; rg < 2; ++rg)
#pragma unroll
    for (int sb = 0; sb < 2; ++sb) {
      int tr = rg * 128 + sb * 64 + srow;
      pA[rg][sb] = (const char*)hbuf + (size_t)(rowb + m0 + tr) * 4096 + scol;
      pB[rg][sb] = (const char*)wo + ((size_t)e * DDIM + n0 + tr) * 4096 + scol;
    }

  int rowB = (lane & 15) << 7;
  int mk = (lane & 7) << 4;
  int q16 = (lane >> 4) << 4;
  int c0 = q16 ^ mk, c1 = (q16 + 64) ^ mk;
  int aO0 = 32768 + wm * 16384 + rowB + c0;
  int aO1 = aO0 - c0 + c1;
  int bO0 = (wn >> 1) * 16384 + ((wn & 1) * 64) * 128 + rowB + c0;
  int bO1 = bO0 - c0 + c1;

#define G2_STA(BUF, RG, KO) do { \
    gll16(pA[RG][0] + (KO), ldsc + (BUF) + 32768 + (RG) * 16384 + sdst); \
    gll16(pA[RG][1] + (KO), ldsc + (BUF) + 32768 + (RG) * 16384 + 8192 + sdst); } while (0)
#define G2_STB(BUF, RG, KO) do { \
    gll16(pB[RG][0] + (KO), ldsc + (BUF) + (RG) * 16384 + sdst); \
    gll16(pB[RG][1] + (KO), ldsc + (BUF) + (RG) * 16384 + 8192 + sdst); } while (0)
#define G2_RDA(BUF, MH) { _Pragma("unroll") for (int mf = 0; mf < 4; ++mf) { \
    af[mf][0] = *(const s16x8*)(ldsc + (BUF) + aO0 + ((MH) * 64 + mf * 16) * 128); \
    af[mf][1] = *(const s16x8*)(ldsc + (BUF) + aO1 + ((MH) * 64 + mf * 16) * 128); } }
#define G2_RDB(BUF) { _Pragma("unroll") for (int nf = 0; nf < 4; ++nf) { \
    bf[nf][0] = *(const s16x8*)(ldsc + (BUF) + bO0 + nf * 2048); \
    bf[nf][1] = *(const s16x8*)(ldsc + (BUF) + bO1 + nf * 2048); } }
#define G2_MM(MH, NH) do { __builtin_amdgcn_s_setprio(1); \
    _Pragma("unroll") for (int mf = 0; mf < 4; ++mf) _Pragma("unroll") for (int nf = 0; nf < 2; ++nf) { \
      acc[(MH)*4+mf][(NH)*2+nf] = __builtin_amdgcn_mfma_f32_16x16x32_bf16(af[mf][0], bf[(NH)*2+nf][0], acc[(MH)*4+mf][(NH)*2+nf], 0, 0, 0); \
      acc[(MH)*4+mf][(NH)*2+nf] = __builtin_amdgcn_mfma_f32_16x16x32_bf16(af[mf][1], bf[(NH)*2+nf][1], acc[(MH)*4+mf][(NH)*2+nf], 0, 0, 0); } \
    __builtin_amdgcn_s_setprio(0); } while (0)

  f32x4 acc[8][4];
#pragma unroll
  for (int a = 0; a < 8; ++a)
#pragma unroll
    for (int b = 0; b < 4; ++b) acc[a][b] = (f32x4){0.f,0.f,0.f,0.f};
  s16x8 af[4][2], bf[4][2];

  // prologue: [aB0, aB1, aA0, aA1, bB0, bB1, bA0]
  G2_STB(0, 0, 0); G2_STB(0, 1, 0); G2_STA(0, 0, 0); G2_STA(0, 1, 0);
  G2_STB(65536, 0, 128); G2_STB(65536, 1, 128); G2_STA(65536, 0, 128);
  VMW6();
  BAR_END();

  const int NIT = HDIM / 128;  // 16 iterations x 2 K-tiles
  for (int i = 0; i < NIT; ++i) {
    const int koC = (2 * i + 1) * 128, koA = (2 * i + 2) * 128, koB = (2 * i + 3) * 128;
    const bool more = (i + 1 < NIT);
    // PH1
    G2_RDA(0, 0); G2_RDB(0);
    G2_STA(65536, 1, koC);
    BAR_MID(); LGKM0();
    G2_MM(0, 0);
    BAR_END();
    // PH2
    if (more) G2_STB(0, 0, koA);
    BAR_MID();
    G2_MM(0, 1);
    BAR_END();
    // PH3
    G2_RDA(0, 1);
    if (more) G2_STB(0, 1, koA);
    BAR_MID(); LGKM0();
    G2_MM(1, 0);
    BAR_END();
    // PH4
    if (more) G2_STA(0, 0, koA);
    BAR_MID();
    G2_MM(1, 1);
    if (more) VMW6(); else VMW0();
    BAR_END();
    // PH5
    G2_RDA(65536, 0); G2_RDB(65536);
    if (more) G2_STA(0, 1, koA);
    BAR_MID(); LGKM0();
    G2_MM(0, 0);
    BAR_END();
    // PH6
    if (more) G2_STB(65536, 0, koB);
    BAR_MID();
    G2_MM(0, 1);
    BAR_END();
    // PH7
    G2_RDA(65536, 1);
    if (more) G2_STB(65536, 1, koB);
    BAR_MID(); LGKM0();
    G2_MM(1, 0);
    BAR_END();
    // PH8
    if (more) G2_STA(65536, 0, koB);
    BAR_MID();
    G2_MM(1, 1);
    if (more) VMW6();
    BAR_END();
  }

  // epilogue: scaled scatter into per-slot ybuf (no atomics)
#pragma unroll
  for (int mf = 0; mf < 8; ++mf)
#pragma unroll
    for (int j = 0; j < 4; ++j) {
      int r = wm * 128 + mf * 16 + ((lane >> 4) << 2) + j;
      int mrow = m0 + r;
      if (mrow < cnt) {
        int tok = listTok[e * LSTRIDE + mrow];
        float wgt = listW[e * LSTRIDE + mrow];
        int slot = listSlot[e * LSTRIDE + mrow];
        size_t base = ((size_t)slot * NTOK + tok) * DDIM + n0 + wn * 64;
#pragma unroll
        for (int nf = 0; nf < 4; ++nf)
          ybuf[base + nf * 16 + (lane & 15)] = f2bf(acc[mf][nf][j] * wgt);
      }
    }
#undef G2_STA
#undef G2_STB
#undef G2_RDA
#undef G2_RDB
#undef G2_MM
}

// ---- reduce: out = y0 + y1 (fp32 out), vectorized ----
__global__ __launch_bounds__(256) void k_reduce(const unsigned short* __restrict__ ybuf,
                                                float* __restrict__ out, int n8) {
  int i = blockIdx.x * blockDim.x + threadIdx.x;
  int stride = gridDim.x * blockDim.x;
  const unsigned short* y0 = ybuf;
  const unsigned short* y1 = ybuf + (size_t)NTOK * DDIM;
  for (; i < n8; i += stride) {
    s16x8 a = *(const s16x8*)(y0 + (size_t)i * 8);
    s16x8 b = *(const s16x8*)(y1 + (size_t)i * 8);
    f32x4 o0, o1;
#pragma unroll
    for (int j = 0; j < 4; ++j) o0[j] = bf2f((unsigned short)a[j]) + bf2f((unsigned short)b[j]);
#pragma unroll
    for (int j = 0; j < 4; ++j) o1[j] = bf2f((unsigned short)a[4 + j]) + bf2f((unsigned short)b[4 + j]);
    f32x4* d = (f32x4*)(out + (size_t)i * 8);
    d[0] = o0; d[1] = o1;
  }
}

extern "C" void kernel_launch(void* const* d_in, const int* in_sizes, int n_in,
                              void* d_out, int out_size, void* d_ws, size_t ws_size,
                              hipStream_t stream) {
  const float* x     = (const float*)d_in[0];
  const float* gw    = (const float*)d_in[1];
  const float* wgate = (const float*)d_in[2];
  const float* win   = (const float*)d_in[3];
  const float* wout  = (const float*)d_in[4];
  float* out = (float*)d_out;

  const size_t LBYTES     = (size_t)NEXP * LSTRIDE * 4;
  const size_t OFF_LIST   = 256;
  const size_t OFF_LISTW  = OFF_LIST + LBYTES;
  const size_t OFF_SLOT   = OFF_LISTW + LBYTES;
  const size_t ZERO_BYTES = OFF_LISTW;                  // ctrl + listTok zeroed (pad safety)
  const size_t OFF_XBF = (size_t)1 << 20;
  const size_t OFF_WG  = OFF_XBF + (size_t)NTOK * DDIM * 2;
  const size_t OFF_WI  = OFF_WG + (size_t)NEXP * HDIM * DDIM * 2;
  const size_t OFF_WO  = OFF_WI + (size_t)NEXP * HDIM * DDIM * 2;
  const size_t OFF_H   = OFF_WO + (size_t)NEXP * DDIM * HDIM * 2;
  const size_t OFF_Y   = OFF_WG;                        // ybuf aliases wgb (dead after gemm1)
  const size_t TOTAL   = OFF_H + (size_t)MAXROWS * HDIM * 2;

  if (ws_size < TOTAL) { k_sentinel<<<1, 64, 0, stream>>>(out); return; }

  char* ws = (char*)d_ws;
  int* ctrl            = (int*)ws;                      // [0..7]=cnt, [8..15]=rowbase
  int* listTok         = (int*)(ws + OFF_LIST);
  float* listW         = (float*)(ws + OFF_LISTW);
  int* listSlot        = (int*)(ws + OFF_SLOT);
  unsigned short* xbf  = (unsigned short*)(ws + OFF_XBF);
  unsigned short* wgb  = (unsigned short*)(ws + OFF_WG);
  unsigned short* wib  = (unsigned short*)(ws + OFF_WI);
  unsigned short* wob  = (unsigned short*)(ws + OFF_WO);
  unsigned short* hbuf = (unsigned short*)(ws + OFF_H);
  unsigned short* ybuf = (unsigned short*)(ws + OFF_Y);

  hipMemsetAsync(ws, 0, ZERO_BYTES, stream);

  k_cvt<<<2048, 256, 0, stream>>>(wgate, wgb, NEXP * HDIM * DDIM / 8);
  k_cvt<<<2048, 256, 0, stream>>>(win,   wib, NEXP * HDIM * DDIM / 8);
  k_cvt<<<2048, 256, 0, stream>>>(wout,  wob, NEXP * DDIM * HDIM / 8);

  k_router<<<NTOK / 4, 256, 0, stream>>>(x, gw, ctrl, listTok, listW, listSlot, xbf);
  k_prefix<<<1, 64, 0, stream>>>(ctrl);

  k_gemm1<<<dim3(HDIM / 128, NTOK / 256, NEXP), 512, 0, stream>>>(xbf, wgb, wib, ctrl, listTok, hbuf);
  k_gemm2<<<dim3(DDIM / 256, NTOK / 256, NEXP), 512, 0, stream>>>(hbuf, wob, ctrl, listTok, listW, listSlot, ybuf);
  k_reduce<<<2048, 256, 0, stream>>>(ybuf, out, NTOK * DDIM / 8);
}

// Round 4
// 367.173 us; speedup vs baseline: 1.8280x; 1.4770x over previous
//
#include <hip/hip_runtime.h>
#include <stdint.h>
#include <stddef.h>

#define NTOK 8192
#define DDIM 1024
#define NEXP 8
#define HDIM 2048
#define LSTRIDE (NTOK + 256)
#define NCHUNK 128                      /* 64 tokens per chunk */
#define MAXROWS (2 * NTOK + NEXP * 256) /* 18432 compacted rows, 256-padded */

typedef __attribute__((ext_vector_type(4))) float f32x4;
typedef __attribute__((ext_vector_type(8))) short s16x8;
typedef __attribute__((ext_vector_type(4))) short s16x4;

static __device__ __forceinline__ unsigned short f2bf(float f) {
  union { float f; unsigned u; } v; v.f = f;
  unsigned r = v.u + 0x7FFFu + ((v.u >> 16) & 1u); // RNE
  return (unsigned short)(r >> 16);
}
static __device__ __forceinline__ float bf2f(unsigned short h) {
  union { unsigned u; float f; } v; v.u = ((unsigned)h) << 16;
  return v.f;
}

static __device__ __forceinline__ void gll16(const void* g, void* l) {
  __builtin_amdgcn_global_load_lds((const __attribute__((address_space(1))) void*)g,
                                   (__attribute__((address_space(3))) void*)l, 16, 0, 0);
}

#define BAR_MID() __builtin_amdgcn_s_barrier()
#define BAR_END() do { __builtin_amdgcn_s_barrier(); __builtin_amdgcn_sched_barrier(0); } while (0)
#define LGKM0() do { asm volatile("s_waitcnt lgkmcnt(0)" ::: "memory"); __builtin_amdgcn_sched_barrier(0); } while (0)
#define VMW6() asm volatile("s_waitcnt vmcnt(6)" ::: "memory")
#define VMW0() asm volatile("s_waitcnt vmcnt(0)" ::: "memory")

__global__ void k_sentinel(float* out) { if (threadIdx.x == 0) out[0] = 1.0e6f; }

// ---- fp32 -> bf16 bulk convert; n8 = count/8 ----
__global__ __launch_bounds__(256) void k_cvt(const float* __restrict__ src,
                                             unsigned short* __restrict__ dst, int n8) {
  int i = blockIdx.x * blockDim.x + threadIdx.x;
  int stride = gridDim.x * blockDim.x;
  for (; i < n8; i += stride) {
    const f32x4* s = (const f32x4*)(src + (size_t)i * 8);
    f32x4 a = s[0], b = s[1];
    s16x8 o;
    o[0] = f2bf(a[0]); o[1] = f2bf(a[1]); o[2] = f2bf(a[2]); o[3] = f2bf(a[3]);
    o[4] = f2bf(b[0]); o[5] = f2bf(b[1]); o[6] = f2bf(b[2]); o[7] = f2bf(b[3]);
    *(s16x8*)(dst + (size_t)i * 8) = o;
  }
}

// ---- router compute: fp32 logits, top-2 (lower-index tie-break), softmax.
//      Writes tokE (packed expert ids) + tokW2 (both weights) + xbf. NO atomics. ----
__global__ __launch_bounds__(256) void k_router(const float* __restrict__ x,
    const float* __restrict__ gw, unsigned* __restrict__ tokE, float2* __restrict__ tokW2,
    unsigned short* __restrict__ xbf) {
  int lane = threadIdx.x & 63;
  int t = blockIdx.x * 4 + (threadIdx.x >> 6);
  const f32x4* x4 = (const f32x4*)x;
  const f32x4* g4 = (const f32x4*)gw;
  f32x4 xr[4];
#pragma unroll
  for (int j = 0; j < 4; ++j) xr[j] = x4[(size_t)t * 256 + j * 64 + lane];
#pragma unroll
  for (int j = 0; j < 4; ++j) {
    s16x4 o;
    o[0] = f2bf(xr[j][0]); o[1] = f2bf(xr[j][1]); o[2] = f2bf(xr[j][2]); o[3] = f2bf(xr[j][3]);
    *(s16x4*)(xbf + (size_t)t * DDIM + (j * 64 + lane) * 4) = o;
  }
  float le[8];
#pragma unroll
  for (int e = 0; e < 8; ++e) {
    float p = 0.f;
#pragma unroll
    for (int j = 0; j < 4; ++j) {
      f32x4 g = g4[e * 256 + j * 64 + lane];
      p += xr[j][0] * g[0] + xr[j][1] * g[1] + xr[j][2] * g[2] + xr[j][3] * g[3];
    }
#pragma unroll
    for (int off = 32; off > 0; off >>= 1) p += __shfl_xor(p, off, 64);
    le[e] = p;
  }
  if (lane == 0) {
    int i0 = 0; float v0 = le[0];
#pragma unroll
    for (int e = 1; e < 8; ++e) if (le[e] > v0) { v0 = le[e]; i0 = e; }
    int i1 = -1; float v1 = 0.f;
#pragma unroll
    for (int e = 0; e < 8; ++e) if (e != i0 && (i1 < 0 || le[e] > v1)) { v1 = le[e]; i1 = e; }
    float b = __expf(v1 - v0);
    float s = 1.f + b;
    tokE[t] = (unsigned)i0 | ((unsigned)i1 << 8);
    tokW2[t] = make_float2(1.f / s, b / s);
  }
}

// ---- per-chunk histogram: cntTable[e][chunk], no global atomics ----
__global__ __launch_bounds__(64) void k_hist(const unsigned* __restrict__ tokE,
                                             int* __restrict__ cntTable) {
  __shared__ int c8[NEXP];
  int tid = threadIdx.x, c = blockIdx.x;
  if (tid < NEXP) c8[tid] = 0;
  __syncthreads();
  unsigned v = tokE[c * 64 + tid];
  atomicAdd(&c8[v & 255], 1);
  atomicAdd(&c8[(v >> 8) & 255], 1);
  __syncthreads();
  if (tid < NEXP) cntTable[tid * NCHUNK + c] = c8[tid];
}

// ---- scan: totals -> ctrl[0..7], 256-padded rowbases -> ctrl[8..15],
//      per-expert exclusive chunk scan -> chunkBaseL ----
__global__ __launch_bounds__(64) void k_scan(const int* __restrict__ cntTable,
                                             int* __restrict__ ctrl, int* __restrict__ cbL) {
  __shared__ int tot[NEXP];
  int e = threadIdx.x;
  if (e < NEXP) {
    int s = 0;
    for (int c = 0; c < NCHUNK; ++c) s += cntTable[e * NCHUNK + c];
    tot[e] = s; ctrl[e] = s;
  }
  __syncthreads();
  if (e == 0) {
    int acc = 0;
    for (int q = 0; q < NEXP; ++q) { ctrl[8 + q] = acc; acc += (tot[q] + 255) & ~255; }
  }
  if (e < NEXP) {
    int run = 0;
    for (int c = 0; c < NCHUNK; ++c) { cbL[e * NCHUNK + c] = run; run += cntTable[e * NCHUNK + c]; }
  }
}

// ---- scatter: place (token, slot) into per-expert lists; LDS atomics only ----
__global__ __launch_bounds__(64) void k_scatter(const unsigned* __restrict__ tokE,
    const float2* __restrict__ tokW2, const int* __restrict__ cbL,
    int* __restrict__ listTok, float* __restrict__ listW, int* __restrict__ listSlot) {
  __shared__ int lcnt[NEXP];
  int tid = threadIdx.x, c = blockIdx.x;
  if (tid < NEXP) lcnt[tid] = 0;
  __syncthreads();
  int t = c * 64 + tid;
  unsigned v = tokE[t];
  int e0 = v & 255, e1 = (v >> 8) & 255;
  float2 w = tokW2[t];
  int l0 = atomicAdd(&lcnt[e0], 1);
  int l1 = atomicAdd(&lcnt[e1], 1);
  int i0 = cbL[e0 * NCHUNK + c] + l0;
  int i1 = cbL[e1 * NCHUNK + c] + l1;
  listTok[e0 * LSTRIDE + i0] = t; listW[e0 * LSTRIDE + i0] = w.x; listSlot[e0 * LSTRIDE + i0] = 0;
  listTok[e1 * LSTRIDE + i1] = t; listW[e1 * LSTRIDE + i1] = w.y; listSlot[e1 * LSTRIDE + i1] = 1;
}

// =====================================================================
// GEMM1: h = silu(Xg @ Wg^T) * (Xg @ Wi^T)
// 8-phase schedule, BM=256, BN(h)=128 dual, BK=64, 8 waves (4M x 2N),
// per-wave 64x64 of g AND i. LDS: bufA/bufB K-tiles, each {Bg,Bi,A0,A1}
// half-tiles of 16 KB, 128 KiB total. XOR swizzle (row&7)<<4 via
// inverse-swizzled global source + swizzled ds_read.
// =====================================================================
__global__ __launch_bounds__(512, 2) void k_gemm1(const unsigned short* __restrict__ xbf,
    const unsigned short* __restrict__ wg, const unsigned short* __restrict__ wi,
    const int* __restrict__ ctrl, const int* __restrict__ listTok,
    unsigned short* __restrict__ hbuf) {
  int e = blockIdx.z;
  int cnt = ctrl[e];
  int m0 = blockIdx.y * 256;
  if (m0 >= cnt) return;
  int rowb = ctrl[8 + e];
  int n0 = blockIdx.x * 128;

  __shared__ __align__(16) char lds[131072];
  char* ldsc = &lds[0];

  int tid = threadIdx.x, lane = tid & 63, wv = tid >> 6;
  int wm = wv >> 1, wn = wv & 1;

  int srow = tid >> 3;
  int scol = (((tid & 7) ^ ((tid >> 3) & 7)) << 4);  // inverse-swizzled source col byte
  int sdst = wv << 10;                               // wave-uniform LDS dest
  const char* pA[2][2];
  const char* pBg[2];
  const char* pBi[2];
#pragma unroll
  for (int rg = 0; rg < 2; ++rg)
#pragma unroll
    for (int sb = 0; sb < 2; ++sb) {
      int tok = listTok[e * LSTRIDE + m0 + rg * 128 + sb * 64 + srow];
      pA[rg][sb] = (const char*)xbf + (size_t)tok * 2048 + scol;
    }
#pragma unroll
  for (int sb = 0; sb < 2; ++sb) {
    pBg[sb] = (const char*)wg + ((size_t)e * HDIM + n0 + sb * 64 + srow) * 2048 + scol;
    pBi[sb] = (const char*)wi + ((size_t)e * HDIM + n0 + sb * 64 + srow) * 2048 + scol;
  }

  int rowB = (lane & 15) << 7;
  int mk = (lane & 7) << 4;
  int q16 = (lane >> 4) << 4;
  int c0 = q16 ^ mk, c1 = (q16 + 64) ^ mk;
  int aO0 = 32768 + (wm >> 1) * 16384 + ((wm & 1) * 64) * 128 + rowB + c0;
  int aO1 = aO0 - c0 + c1;
  int gO0 = (wn * 64) * 128 + rowB + c0;
  int gO1 = gO0 - c0 + c1;
  int iO0 = 16384 + (wn * 64) * 128 + rowB + c0;
  int iO1 = iO0 - c0 + c1;

#define G1_STA(BUF, RG, KO) do { \
    gll16(pA[RG][0] + (KO), ldsc + (BUF) + 32768 + (RG) * 16384 + sdst); \
    gll16(pA[RG][1] + (KO), ldsc + (BUF) + 32768 + (RG) * 16384 + 8192 + sdst); } while (0)
#define G1_STG(BUF, KO) do { \
    gll16(pBg[0] + (KO), ldsc + (BUF) + sdst); \
    gll16(pBg[1] + (KO), ldsc + (BUF) + 8192 + sdst); } while (0)
#define G1_STI(BUF, KO) do { \
    gll16(pBi[0] + (KO), ldsc + (BUF) + 16384 + sdst); \
    gll16(pBi[1] + (KO), ldsc + (BUF) + 16384 + 8192 + sdst); } while (0)
#define G1_RDA(BUF) { _Pragma("unroll") for (int mf = 0; mf < 4; ++mf) { \
    af[mf][0] = *(const s16x8*)(ldsc + (BUF) + aO0 + mf * 2048); \
    af[mf][1] = *(const s16x8*)(ldsc + (BUF) + aO1 + mf * 2048); } }
#define G1_RDG(BUF) { _Pragma("unroll") for (int nf = 0; nf < 4; ++nf) { \
    bg[nf][0] = *(const s16x8*)(ldsc + (BUF) + gO0 + nf * 2048); \
    bg[nf][1] = *(const s16x8*)(ldsc + (BUF) + gO1 + nf * 2048); } }
#define G1_RDI(BUF) { _Pragma("unroll") for (int nf = 0; nf < 4; ++nf) { \
    bi[nf][0] = *(const s16x8*)(ldsc + (BUF) + iO0 + nf * 2048); \
    bi[nf][1] = *(const s16x8*)(ldsc + (BUF) + iO1 + nf * 2048); } }
#define G1_MMG(NH) do { __builtin_amdgcn_s_setprio(1); \
    _Pragma("unroll") for (int mf = 0; mf < 4; ++mf) _Pragma("unroll") for (int nf = 0; nf < 2; ++nf) { \
      accg[mf][(NH)*2+nf] = __builtin_amdgcn_mfma_f32_16x16x32_bf16(af[mf][0], bg[(NH)*2+nf][0], accg[mf][(NH)*2+nf], 0, 0, 0); \
      accg[mf][(NH)*2+nf] = __builtin_amdgcn_mfma_f32_16x16x32_bf16(af[mf][1], bg[(NH)*2+nf][1], accg[mf][(NH)*2+nf], 0, 0, 0); } \
    __builtin_amdgcn_s_setprio(0); } while (0)
#define G1_MMI(NH) do { __builtin_amdgcn_s_setprio(1); \
    _Pragma("unroll") for (int mf = 0; mf < 4; ++mf) _Pragma("unroll") for (int nf = 0; nf < 2; ++nf) { \
      acci[mf][(NH)*2+nf] = __builtin_amdgcn_mfma_f32_16x16x32_bf16(af[mf][0], bi[(NH)*2+nf][0], acci[mf][(NH)*2+nf], 0, 0, 0); \
      acci[mf][(NH)*2+nf] = __builtin_amdgcn_mfma_f32_16x16x32_bf16(af[mf][1], bi[(NH)*2+nf][1], acci[mf][(NH)*2+nf], 0, 0, 0); } \
    __builtin_amdgcn_s_setprio(0); } while (0)

  f32x4 accg[4][4], acci[4][4];
#pragma unroll
  for (int a = 0; a < 4; ++a)
#pragma unroll
    for (int b = 0; b < 4; ++b) { accg[a][b] = (f32x4){0.f,0.f,0.f,0.f}; acci[a][b] = (f32x4){0.f,0.f,0.f,0.f}; }
  s16x8 af[4][2], bg[4][2], bi[4][2];

  G1_STG(0, 0); G1_STA(0, 0, 0); G1_STI(0, 0); G1_STA(0, 1, 0);
  G1_STG(65536, 128); G1_STA(65536, 0, 128); G1_STI(65536, 128);
  VMW6();
  BAR_END();

  const int NIT = DDIM / 128;
  for (int i = 0; i < NIT; ++i) {
    const int koC = (2 * i + 1) * 128, koA = (2 * i + 2) * 128, koB = (2 * i + 3) * 128;
    const bool more = (i + 1 < NIT);
    G1_RDA(0); G1_RDG(0);
    G1_STA(65536, 1, koC);
    BAR_MID(); LGKM0();
    G1_MMG(0);
    BAR_END();
    if (more) G1_STG(0, koA);
    BAR_MID();
    G1_MMG(1);
    BAR_END();
    G1_RDI(0);
    if (more) G1_STA(0, 0, koA);
    BAR_MID(); LGKM0();
    G1_MMI(0);
    BAR_END();
    if (more) G1_STI(0, koA);
    BAR_MID();
    G1_MMI(1);
    if (more) VMW6(); else VMW0();
    BAR_END();
    G1_RDA(65536); G1_RDG(65536);
    if (more) G1_STA(0, 1, koA);
    BAR_MID(); LGKM0();
    G1_MMG(0);
    BAR_END();
    if (more) G1_STG(65536, koB);
    BAR_MID();
    G1_MMG(1);
    BAR_END();
    G1_RDI(65536);
    if (more) G1_STA(65536, 0, koB);
    BAR_MID(); LGKM0();
    G1_MMI(0);
    BAR_END();
    if (more) G1_STI(65536, koB);
    BAR_MID();
    G1_MMI(1);
    if (more) VMW6();
    BAR_END();
  }

#pragma unroll
  for (int mf = 0; mf < 4; ++mf)
#pragma unroll
    for (int j = 0; j < 4; ++j) {
      int r = wm * 64 + mf * 16 + ((lane >> 4) << 2) + j;
      size_t rowoff = (size_t)(rowb + m0 + r) * HDIM;
#pragma unroll
      for (int nf = 0; nf < 4; ++nf) {
        int cc = n0 + wn * 64 + nf * 16 + (lane & 15);
        float g = accg[mf][nf][j];
        float iv = acci[mf][nf][j];
        float hv = g / (1.f + __expf(-g)) * iv;
        hbuf[rowoff + cc] = f2bf(hv);
      }
    }
#undef G1_STA
#undef G1_STG
#undef G1_STI
#undef G1_RDA
#undef G1_RDG
#undef G1_RDI
#undef G1_MMG
#undef G1_MMI
}

// =====================================================================
// GEMM2: y[slot][token] = w * (h @ Wo^T)
// 8-phase, BM=256, BN=256, BK=64, 8 waves (2M x 4N), per-wave 128x64.
// =====================================================================
__global__ __launch_bounds__(512, 2) void k_gemm2(const unsigned short* __restrict__ hbuf,
    const unsigned short* __restrict__ wo, const int* __restrict__ ctrl,
    const int* __restrict__ listTok, const float* __restrict__ listW,
    const int* __restrict__ listSlot, unsigned short* __restrict__ ybuf) {
  int e = blockIdx.z;
  int cnt = ctrl[e];
  int m0 = blockIdx.y * 256;
  if (m0 >= cnt) return;
  int rowb = ctrl[8 + e];
  int n0 = blockIdx.x * 256;

  __shared__ __align__(16) char lds[131072];
  char* ldsc = &lds[0];

  int tid = threadIdx.x, lane = tid & 63, wv = tid >> 6;
  int wm = wv >> 2, wn = wv & 3;

  int srow = tid >> 3;
  int scol = (((tid & 7) ^ ((tid >> 3) & 7)) << 4);
  int sdst = wv << 10;
  const char* pA[2][2];
  const char* pB[2][2];
#pragma unroll
  for (int rg = 0; rg < 2; ++rg)
#pragma unroll
    for (int sb = 0; sb < 2; ++sb) {
      int tr = rg * 128 + sb * 64 + srow;
      pA[rg][sb] = (const char*)hbuf + (size_t)(rowb + m0 + tr) * 4096 + scol;
      pB[rg][sb] = (const char*)wo + ((size_t)e * DDIM + n0 + tr) * 4096 + scol;
    }

  int rowB = (lane & 15) << 7;
  int mk = (lane & 7) << 4;
  int q16 = (lane >> 4) << 4;
  int c0 = q16 ^ mk, c1 = (q16 + 64) ^ mk;
  int aO0 = 32768 + wm * 16384 + rowB + c0;
  int aO1 = aO0 - c0 + c1;
  int bO0 = (wn >> 1) * 16384 + ((wn & 1) * 64) * 128 + rowB + c0;
  int bO1 = bO0 - c0 + c1;

#define G2_STA(BUF, RG, KO) do { \
    gll16(pA[RG][0] + (KO), ldsc + (BUF) + 32768 + (RG) * 16384 + sdst); \
    gll16(pA[RG][1] + (KO), ldsc + (BUF) + 32768 + (RG) * 16384 + 8192 + sdst); } while (0)
#define G2_STB(BUF, RG, KO) do { \
    gll16(pB[RG][0] + (KO), ldsc + (BUF) + (RG) * 16384 + sdst); \
    gll16(pB[RG][1] + (KO), ldsc + (BUF) + (RG) * 16384 + 8192 + sdst); } while (0)
#define G2_RDA(BUF, MH) { _Pragma("unroll") for (int mf = 0; mf < 4; ++mf) { \
    af[mf][0] = *(const s16x8*)(ldsc + (BUF) + aO0 + ((MH) * 64 + mf * 16) * 128); \
    af[mf][1] = *(const s16x8*)(ldsc + (BUF) + aO1 + ((MH) * 64 + mf * 16) * 128); } }
#define G2_RDB(BUF) { _Pragma("unroll") for (int nf = 0; nf < 4; ++nf) { \
    bf[nf][0] = *(const s16x8*)(ldsc + (BUF) + bO0 + nf * 2048); \
    bf[nf][1] = *(const s16x8*)(ldsc + (BUF) + bO1 + nf * 2048); } }
#define G2_MM(MH, NH) do { __builtin_amdgcn_s_setprio(1); \
    _Pragma("unroll") for (int mf = 0; mf < 4; ++mf) _Pragma("unroll") for (int nf = 0; nf < 2; ++nf) { \
      acc[(MH)*4+mf][(NH)*2+nf] = __builtin_amdgcn_mfma_f32_16x16x32_bf16(af[mf][0], bf[(NH)*2+nf][0], acc[(MH)*4+mf][(NH)*2+nf], 0, 0, 0); \
      acc[(MH)*4+mf][(NH)*2+nf] = __builtin_amdgcn_mfma_f32_16x16x32_bf16(af[mf][1], bf[(NH)*2+nf][1], acc[(MH)*4+mf][(NH)*2+nf], 0, 0, 0); } \
    __builtin_amdgcn_s_setprio(0); } while (0)

  f32x4 acc[8][4];
#pragma unroll
  for (int a = 0; a < 8; ++a)
#pragma unroll
    for (int b = 0; b < 4; ++b) acc[a][b] = (f32x4){0.f,0.f,0.f,0.f};
  s16x8 af[4][2], bf[4][2];

  G2_STB(0, 0, 0); G2_STB(0, 1, 0); G2_STA(0, 0, 0); G2_STA(0, 1, 0);
  G2_STB(65536, 0, 128); G2_STB(65536, 1, 128); G2_STA(65536, 0, 128);
  VMW6();
  BAR_END();

  const int NIT = HDIM / 128;
  for (int i = 0; i < NIT; ++i) {
    const int koC = (2 * i + 1) * 128, koA = (2 * i + 2) * 128, koB = (2 * i + 3) * 128;
    const bool more = (i + 1 < NIT);
    G2_RDA(0, 0); G2_RDB(0);
    G2_STA(65536, 1, koC);
    BAR_MID(); LGKM0();
    G2_MM(0, 0);
    BAR_END();
    if (more) G2_STB(0, 0, koA);
    BAR_MID();
    G2_MM(0, 1);
    BAR_END();
    G2_RDA(0, 1);
    if (more) G2_STB(0, 1, koA);
    BAR_MID(); LGKM0();
    G2_MM(1, 0);
    BAR_END();
    if (more) G2_STA(0, 0, koA);
    BAR_MID();
    G2_MM(1, 1);
    if (more) VMW6(); else VMW0();
    BAR_END();
    G2_RDA(65536, 0); G2_RDB(65536);
    if (more) G2_STA(0, 1, koA);
    BAR_MID(); LGKM0();
    G2_MM(0, 0);
    BAR_END();
    if (more) G2_STB(65536, 0, koB);
    BAR_MID();
    G2_MM(0, 1);
    BAR_END();
    G2_RDA(65536, 1);
    if (more) G2_STB(65536, 1, koB);
    BAR_MID(); LGKM0();
    G2_MM(1, 0);
    BAR_END();
    if (more) G2_STA(65536, 0, koB);
    BAR_MID();
    G2_MM(1, 1);
    if (more) VMW6();
    BAR_END();
  }

#pragma unroll
  for (int mf = 0; mf < 8; ++mf)
#pragma unroll
    for (int j = 0; j < 4; ++j) {
      int r = wm * 128 + mf * 16 + ((lane >> 4) << 2) + j;
      int mrow = m0 + r;
      if (mrow < cnt) {
        int tok = listTok[e * LSTRIDE + mrow];
        float wgt = listW[e * LSTRIDE + mrow];
        int slot = listSlot[e * LSTRIDE + mrow];
        size_t base = ((size_t)slot * NTOK + tok) * DDIM + n0 + wn * 64;
#pragma unroll
        for (int nf = 0; nf < 4; ++nf)
          ybuf[base + nf * 16 + (lane & 15)] = f2bf(acc[mf][nf][j] * wgt);
      }
    }
#undef G2_STA
#undef G2_STB
#undef G2_RDA
#undef G2_RDB
#undef G2_MM
}

// ---- reduce: out = y0 + y1 (fp32 out), vectorized ----
__global__ __launch_bounds__(256) void k_reduce(const unsigned short* __restrict__ ybuf,
                                                float* __restrict__ out, int n8) {
  int i = blockIdx.x * blockDim.x + threadIdx.x;
  int stride = gridDim.x * blockDim.x;
  const unsigned short* y0 = ybuf;
  const unsigned short* y1 = ybuf + (size_t)NTOK * DDIM;
  for (; i < n8; i += stride) {
    s16x8 a = *(const s16x8*)(y0 + (size_t)i * 8);
    s16x8 b = *(const s16x8*)(y1 + (size_t)i * 8);
    f32x4 o0, o1;
#pragma unroll
    for (int j = 0; j < 4; ++j) o0[j] = bf2f((unsigned short)a[j]) + bf2f((unsigned short)b[j]);
#pragma unroll
    for (int j = 0; j < 4; ++j) o1[j] = bf2f((unsigned short)a[4 + j]) + bf2f((unsigned short)b[4 + j]);
    f32x4* d = (f32x4*)(out + (size_t)i * 8);
    d[0] = o0; d[1] = o1;
  }
}

extern "C" void kernel_launch(void* const* d_in, const int* in_sizes, int n_in,
                              void* d_out, int out_size, void* d_ws, size_t ws_size,
                              hipStream_t stream) {
  const float* x     = (const float*)d_in[0];
  const float* gw    = (const float*)d_in[1];
  const float* wgate = (const float*)d_in[2];
  const float* win   = (const float*)d_in[3];
  const float* wout  = (const float*)d_in[4];
  float* out = (float*)d_out;

  const size_t LBYTES     = (size_t)NEXP * LSTRIDE * 4;
  const size_t OFF_LIST   = 256;
  const size_t OFF_LISTW  = OFF_LIST + LBYTES;          // zero range end
  const size_t ZERO_BYTES = OFF_LISTW;                  // ctrl + listTok zeroed (pad safety)
  const size_t OFF_SLOT   = OFF_LISTW + LBYTES;
  const size_t OFF_CB     = OFF_SLOT + LBYTES;          // chunkBaseL 8*128 ints
  const size_t OFF_CT     = OFF_CB + 4096;              // cntTable  8*128 ints
  const size_t OFF_TE     = OFF_CT + 4096;              // tokE: NTOK u32
  const size_t OFF_TW     = OFF_TE + (size_t)NTOK * 4;  // tokW2: NTOK float2
  const size_t OFF_XBF = (size_t)1 << 20;
  const size_t OFF_WG  = OFF_XBF + (size_t)NTOK * DDIM * 2;
  const size_t OFF_WI  = OFF_WG + (size_t)NEXP * HDIM * DDIM * 2;
  const size_t OFF_WO  = OFF_WI + (size_t)NEXP * HDIM * DDIM * 2;
  const size_t OFF_H   = OFF_WO + (size_t)NEXP * DDIM * HDIM * 2;
  const size_t OFF_Y   = OFF_WG;                        // ybuf aliases wgb (dead after gemm1)
  const size_t TOTAL   = OFF_H + (size_t)MAXROWS * HDIM * 2;

  if (ws_size < TOTAL) { k_sentinel<<<1, 64, 0, stream>>>(out); return; }

  char* ws = (char*)d_ws;
  int* ctrl            = (int*)ws;                      // [0..7]=cnt, [8..15]=rowbase
  int* listTok         = (int*)(ws + OFF_LIST);
  float* listW         = (float*)(ws + OFF_LISTW);
  int* listSlot        = (int*)(ws + OFF_SLOT);
  int* cbL             = (int*)(ws + OFF_CB);
  int* cntTable        = (int*)(ws + OFF_CT);
  unsigned* tokE       = (unsigned*)(ws + OFF_TE);
  float2* tokW2        = (float2*)(ws + OFF_TW);
  unsigned short* xbf  = (unsigned short*)(ws + OFF_XBF);
  unsigned short* wgb  = (unsigned short*)(ws + OFF_WG);
  unsigned short* wib  = (unsigned short*)(ws + OFF_WI);
  unsigned short* wob  = (unsigned short*)(ws + OFF_WO);
  unsigned short* hbuf = (unsigned short*)(ws + OFF_H);
  unsigned short* ybuf = (unsigned short*)(ws + OFF_Y);

  hipMemsetAsync(ws, 0, ZERO_BYTES, stream);

  k_router<<<NTOK / 4, 256, 0, stream>>>(x, gw, tokE, tokW2, xbf);
  k_hist<<<NCHUNK, 64, 0, stream>>>(tokE, cntTable);
  k_scan<<<1, 64, 0, stream>>>(cntTable, ctrl, cbL);
  k_scatter<<<NCHUNK, 64, 0, stream>>>(tokE, tokW2, cbL, listTok, listW, listSlot);

  k_cvt<<<2048, 256, 0, stream>>>(wgate, wgb, NEXP * HDIM * DDIM / 8);
  k_cvt<<<2048, 256, 0, stream>>>(win,   wib, NEXP * HDIM * DDIM / 8);
  k_cvt<<<2048, 256, 0, stream>>>(wout,  wob, NEXP * DDIM * HDIM / 8);

  k_gemm1<<<dim3(HDIM / 128, NTOK / 256, NEXP), 512, 0, stream>>>(xbf, wgb, wib, ctrl, listTok, hbuf);
  k_gemm2<<<dim3(DDIM / 256, NTOK / 256, NEXP), 512, 0, stream>>>(hbuf, wob, ctrl, listTok, listW, listSlot, ybuf);
  k_reduce<<<2048, 256, 0, stream>>>(ybuf, out, NTOK * DDIM / 8);
}